// Round 14
// baseline (867.149 us; speedup 1.0000x reference)
//
#include <hip/hip_runtime.h>

typedef __attribute__((ext_vector_type(8))) short short8;
typedef __attribute__((ext_vector_type(4))) int int4v;
typedef __attribute__((ext_vector_type(4))) float f32x4;

#define MFMA(a, b, c) __builtin_amdgcn_mfma_f32_16x16x32_bf16(a, b, c, 0, 0, 0)
#define SCALE 0.17677669529663687f

__device__ __forceinline__ short f2bf(float f) {
  union { float f; unsigned u; } v;
  v.f = f;
  unsigned r = v.u + 0x7fffu + ((v.u >> 16) & 1u);
  return (short)(r >> 16);
}

__device__ __forceinline__ unsigned cvt_pk(float lo, float hi) {
  unsigned r;
  asm("v_cvt_pk_bf16_f32 %0, %1, %2" : "=v"(r) : "v"(lo), "v"(hi));
  return r;
}

// K1 LDS map (81,456 B -> 2 blocks/CU exactly: 2x81,920 = 160 KiB):
//   [0,16384)      vT[128][64] bf16, swizzle byte^=(d&7)<<4
//   [16384,28928)  Q[49][128] bf16, 256B/row, swizzle byte^=(row&7)<<4
//   [28928,41472)  K[49][128] bf16, same layout
//   [41472,81456)  x panel [49][XS_STR] bf16 (dead after P2; P scratch aliases it)
#define VT_OFF 0
#define Q_OFF  16384
#define K_OFF  28928
#define XP_OFF 41472
#define XS_STR 408    // 816B/row: %16==0; 2-way bank alias only (free)
#define AO_STR 392

// merged prep: weight transpose/cast + bias table in one launch
__global__ void prep_all(const float* __restrict__ wqkv,
                         const float* __restrict__ wout,
                         const float* __restrict__ pe,
                         short* __restrict__ wqkvT,
                         short* __restrict__ woutT,
                         float* __restrict__ btabT) {
  int i = blockIdx.x * 256 + threadIdx.x;
  if (i < 1152 * 384) {                  // wqkvT[n][k] = wqkv[k][n]; Q rows pre-scaled
    int n = i / 384, k = i - (i / 384) * 384;
    float w = wqkv[k * 1152 + n];
    if (n < 384) w *= SCALE;
    wqkvT[i] = f2bf(w);
  }
  if (i < 384 * 384) {                   // woutT[n][k] = wout[k][n]
    int n = i / 384, k = i - (i / 384) * 384;
    woutT[i] = f2bf(wout[k * 384 + n]);
  }
  if (i < 16384) {                       // btabT[t][i][c][nt] = bias(i, j=nt*16+c)
    int t = i >> 12;
    int ii = (i >> 6) & 63;
    int j = i & 63;
    float v;
    if (ii < 49 && j < 49) {
      int ai = ii / 7, bi = ii - ai * 7, aj = j / 7, bj = j - aj * 7;
      v = pe[(aj - ai + 6) * 13 + (bj - bi + 6)];
      if ((t & 1) && ((ii >= 28) != (j >= 28))) v = -1e30f;
      if ((t & 2) && ((bi >= 4) != (bj >= 4))) v = -1e30f;
    } else if (j < 49) {
      v = 0.f;
    } else {
      v = -1e30f;
    }
    btabT[((t * 64 + ii) * 16 + (j & 15)) * 4 + (j >> 4)] = v;
  }
}

// ---------------- K1: QKV GEMM (4-head slice) + windowed attention ----------------
// (unchanged from R13: 289 us, 2 blocks/CU, no spill)
__global__ __launch_bounds__(512, 4) void swin_qkv_attn(
    const float* __restrict__ x, const short* __restrict__ wqkvT,
    const float* __restrict__ btabT, short* __restrict__ aout) {

  __shared__ short8 smem[5091];   // 81,456 B, see map above
  char* smc = (char*)smem;
  short* xpan = (short*)(smc + XP_OFF);

  const int tid = threadIdx.x;
  const int lane = tid & 63;
  const int wv = tid >> 6;
  const int l15 = lane & 15;
  const int lhi = lane >> 4;

  // XCD-chunked bijective swizzle (6144 % 8 == 0)
  const int bid = blockIdx.x;
  const int sw = (bid & 7) * 768 + (bid >> 3);
  const int g = sw - (sw / 3) * 3;
  const int bw = sw / 3;
  const int batch = bw >> 6;
  const int win = bw & 63;
  const int wy = win >> 3, wx = win & 7;

  const size_t xbase = (size_t)batch * (56 * 56 * 384);
  const f32x4 zf = {0.f, 0.f, 0.f, 0.f};

  // ---- Phase 1: x window -> x panel (one token per thread-octet) ----
  {
    const int tok = tid >> 3;          // 0..63
    const int sub = tid & 7;
    if (tok < 49) {
      int iy = (tok * 37) >> 8;
      int ix = tok - iy * 7;
      int rr = wy * 7 + iy + 3; if (rr >= 56) rr -= 56;
      int cc = wx * 7 + ix + 3; if (cc >= 56) cc -= 56;
      const float* xp = x + xbase + (size_t)(rr * 56 + cc) * 384;
#pragma unroll
      for (int j = 0; j < 6; ++j) {
        const int c8 = (sub + 8 * j) * 8;   // 8-float chunk
        const float4 fa = *(const float4*)(xp + c8);
        const float4 fb = *(const float4*)(xp + c8 + 4);
        int4v p;
        p.x = (int)cvt_pk(fa.x, fa.y);
        p.y = (int)cvt_pk(fa.z, fa.w);
        p.z = (int)cvt_pk(fb.x, fb.y);
        p.w = (int)cvt_pk(fb.z, fb.w);
        *(int4v*)(&xpan[tok * XS_STR + c8]) = p;
      }
    }
  }
  __syncthreads();   // barrier 1: x panel complete

  // ---- Phase 2: QKV GEMM for head group g ----
  f32x4 acc[4][3];
  const int n0 = wv * 48;
  {
    const short* pB[3];
#pragma unroll
    for (int n = 0; n < 3; ++n) {
      const int c0 = n0 + n * 16;
      const int seg = c0 >> 7;             // 0=q 1=k 2=v
      const int hloc = (c0 >> 5) & 3;
      const int wrow = seg * 384 + (g * 4 + hloc) * 32 + (c0 & 31);
      pB[n] = wqkvT + (size_t)(wrow + l15) * 384 + lhi * 8;
    }
#pragma unroll
    for (int m = 0; m < 4; ++m)
#pragma unroll
      for (int n = 0; n < 3; ++n) acc[m][n] = zf;

    const short* pA[4];
#pragma unroll
    for (int m = 0; m < 4; ++m) {
      int row = m * 16 + l15;
      int rc = row < 49 ? row : 48;
      pA[m] = &xpan[rc * XS_STR + lhi * 8];
    }

#pragma unroll
    for (int k = 0; k < 12; ++k) {
      const short8 b0 = *(const short8*)(pB[0] + k * 32);
      const short8 b1 = *(const short8*)(pB[1] + k * 32);
      const short8 b2 = *(const short8*)(pB[2] + k * 32);
#pragma unroll
      for (int m = 0; m < 4; ++m) {
        const short8 a = *(const short8*)(pA[m] + k * 32);
        acc[m][0] = MFMA(a, b0, acc[m][0]);
        acc[m][1] = MFMA(a, b1, acc[m][1]);
        acc[m][2] = MFMA(a, b2, acc[m][2]);
      }
    }
  }

  // ---- Epilogue: acc -> vT | Q | K (disjoint from x panel -> no barrier before) ----
  {
#pragma unroll
    for (int n = 0; n < 3; ++n) {
      const int c0 = n0 + n * 16;
      if (c0 < 256) {
#pragma unroll
        for (int m = 0; m < 4; ++m)
#pragma unroll
          for (int r = 0; r < 4; ++r) {
            const int row = m * 16 + lhi * 4 + r;
            if (row < 49) {
              const int f = c0 + l15;                 // 0..255: Q then K
              const int base = (f < 128) ? Q_OFF : K_OFF;
              const int fo = (f & 127) * 2;
              *(short*)(smc + base + row * 256 + (fo ^ ((row & 7) << 4))) =
                  f2bf(acc[m][n][r]);
            }
          }
      } else {
        // V: pack row pairs with cvt_pk (no row guard; j>=49 garbage killed by P=0)
        const int d = c0 - 256 + l15;
        char* vrow = smc + VT_OFF + d * 128;
        const int dx = (d & 7) << 4;
#pragma unroll
        for (int m = 0; m < 4; ++m)
#pragma unroll
          for (int r = 0; r < 4; r += 2) {
            const int row = m * 16 + lhi * 4 + r;
            const unsigned pk = cvt_pk(acc[m][n][r], acc[m][n][r + 1]);
            *(unsigned*)(vrow + ((2 * row) ^ dx)) = pk;
          }
      }
    }
  }
  __syncthreads();   // barrier 2: Q/K/vT complete — phase 3 barrier-free

  // ---- Phase 3: attention — one task per wave, fully desynced ----
  {
    const int hl = wv >> 1;
    const int mh = wv & 1;
    const int tt = (wy == 7 ? 1 : 0) | (wx == 7 ? 2 : 0);

    f32x4 bb[2][4];
#pragma unroll
    for (int mi = 0; mi < 2; ++mi)
#pragma unroll
      for (int r = 0; r < 4; ++r) {
        const int i = mh * 32 + mi * 16 + lhi * 4 + r;
        bb[mi][r] = *(const f32x4*)(&btabT[((tt * 64 + i) * 16 + l15) * 4]);
      }

    short8 qa[2];
#pragma unroll
    for (int mi = 0; mi < 2; ++mi) {
      int row = mh * 32 + mi * 16 + l15;
      int rc = row < 49 ? row : 48;
      qa[mi] = *(const short8*)(smc + Q_OFF + rc * 256 +
                                ((hl * 64 + lhi * 16) ^ ((rc & 7) << 4)));
    }
    f32x4 s[2][4];
#pragma unroll
    for (int nt = 0; nt < 4; ++nt) {
      int jr = nt * 16 + l15;
      int jc = jr < 49 ? jr : 48;          // garbage cols killed by bias -1e30
      short8 kb = *(const short8*)(smc + K_OFF + jc * 256 +
                                   ((hl * 64 + lhi * 16) ^ ((jc & 7) << 4)));
#pragma unroll
      for (int mi = 0; mi < 2; ++mi) s[mi][nt] = MFMA(qa[mi], kb, zf);
    }

#pragma unroll
    for (int mi = 0; mi < 2; ++mi)
#pragma unroll
      for (int r = 0; r < 4; ++r)
#pragma unroll
        for (int nt = 0; nt < 4; ++nt)
          s[mi][nt][r] += bb[mi][r][nt];

#pragma unroll
    for (int mi = 0; mi < 2; ++mi)
#pragma unroll
      for (int r = 0; r < 4; ++r) {
        float mx = fmaxf(fmaxf(s[mi][0][r], s[mi][1][r]),
                         fmaxf(s[mi][2][r], s[mi][3][r]));
        mx = fmaxf(mx, __shfl_xor(mx, 1));
        mx = fmaxf(mx, __shfl_xor(mx, 2));
        mx = fmaxf(mx, __shfl_xor(mx, 4));
        mx = fmaxf(mx, __shfl_xor(mx, 8));
        float p0 = __expf(s[mi][0][r] - mx);
        float p1 = __expf(s[mi][1][r] - mx);
        float p2 = __expf(s[mi][2][r] - mx);
        float p3 = __expf(s[mi][3][r] - mx);
        float sum = p0 + p1 + p2 + p3;
        sum += __shfl_xor(sum, 1);
        sum += __shfl_xor(sum, 2);
        sum += __shfl_xor(sum, 4);
        sum += __shfl_xor(sum, 8);
        const float inv = __builtin_amdgcn_rcpf(sum);
        s[mi][0][r] = p0 * inv;
        s[mi][1][r] = p1 * inv;
        s[mi][2][r] = p2 * inv;
        s[mi][3][r] = p3 * inv;
      }

    // P scratch aliases the dead x panel — wave-private, no barrier needed
    char* Pb = smc + XP_OFF + wv * 2304;   // 16 rows x 144B
    f32x4 O[2][2];
#pragma unroll
    for (int mi = 0; mi < 2; ++mi) {
#pragma unroll
      for (int r = 0; r < 4; ++r) {
        const int rowl = lhi * 4 + r;
        short* pr = (short*)(Pb + rowl * 144);
        pr[ 0 + l15] = f2bf(s[mi][0][r]);
        pr[16 + l15] = f2bf(s[mi][1][r]);
        pr[32 + l15] = f2bf(s[mi][2][r]);
        pr[48 + l15] = f2bf(s[mi][3][r]);
      }
      const short8 pa0 = *(const short8*)(Pb + l15 * 144 +  0 + lhi * 16);
      const short8 pa1 = *(const short8*)(Pb + l15 * 144 + 64 + lhi * 16);
#pragma unroll
      for (int n2 = 0; n2 < 2; ++n2) {
        const int dg = hl * 32 + n2 * 16 + l15;
        const short8 v0 = *(const short8*)(smc + VT_OFF + dg * 128 +
                              ((lhi * 16) ^ ((dg & 7) << 4)));
        const short8 v1 = *(const short8*)(smc + VT_OFF + dg * 128 +
                              ((64 + lhi * 16) ^ ((dg & 7) << 4)));
        O[mi][n2] = MFMA(pa0, v0, zf);
        O[mi][n2] = MFMA(pa1, v1, O[mi][n2]);
      }
    }

    short* ab = aout + (size_t)bw * (49 * 384) + (g * 4 + hl) * 32;
#pragma unroll
    for (int mi = 0; mi < 2; ++mi)
#pragma unroll
      for (int n2 = 0; n2 < 2; ++n2)
#pragma unroll
        for (int r = 0; r < 4; ++r) {
          int row = mh * 32 + mi * 16 + lhi * 4 + r;
          if (row < 49) ab[row * 384 + n2 * 16 + l15] = f2bf(O[mi][n2][r]);
        }
  }
}

// ---------------- K2: out-proj, n-split for occupancy (target 4 blocks/CU) ----------------
__global__ __launch_bounds__(512, 6) void swin_outproj(
    const short* __restrict__ aout, const short* __restrict__ woutT,
    const float* __restrict__ bout, float* __restrict__ out) {

  __shared__ short ao[49 * AO_STR];   // 38,416 B -> 4 blocks/CU if regs <= 64

  const int tid = threadIdx.x;
  const int lane = tid & 63;
  const int wv = tid >> 6;
  const int l15 = lane & 15;
  const int lhi = lane >> 4;

  const int bw = blockIdx.x;
  const int batch = bw >> 6;
  const int win = bw & 63;
  const int wy = win >> 3, wx = win & 7;

  const size_t xbase = (size_t)batch * (56 * 56 * 384);
  const f32x4 zf = {0.f, 0.f, 0.f, 0.f};

  const short* abg = aout + (size_t)bw * (49 * 384);
  for (int t = tid; t < 49 * 48; t += 512) {
    int row = t / 48;
    int seg = t - row * 48;
    *(short8*)(&ao[row * AO_STR + seg * 8]) = *(const short8*)(&abg[row * 384 + seg * 8]);
  }
  __syncthreads();

  const short* pA[4];
#pragma unroll
  for (int m = 0; m < 4; ++m) {
    int row = m * 16 + l15;
    int rc = row < 49 ? row : 48;
    pA[m] = &ao[rc * AO_STR + lhi * 8];
  }

#pragma unroll 1   // keep n-tiles separate: acc stays 16 AGPR
  for (int nt = 0; nt < 3; ++nt) {
    const int c0 = wv * 48 + nt * 16;
    const short* pBn = woutT + (size_t)(c0 + l15) * 384 + lhi * 8;

    f32x4 acc[4];
#pragma unroll
    for (int m = 0; m < 4; ++m) acc[m] = zf;

#pragma unroll
    for (int k = 0; k < 12; ++k) {
      const short8 b = *(const short8*)(pBn + k * 32);
#pragma unroll
      for (int m = 0; m < 4; ++m) {
        const short8 a = *(const short8*)(pA[m] + k * 32);
        acc[m] = MFMA(a, b, acc[m]);
      }
    }

    const float bo = bout[c0 + l15];
#pragma unroll
    for (int m = 0; m < 4; ++m)
#pragma unroll
      for (int r = 0; r < 4; ++r) {
        const int row = m * 16 + lhi * 4 + r;
        if (row < 49) {
          int iy = (row * 37) >> 8, ix = row - iy * 7;
          int rr = wy * 7 + iy + 3; if (rr >= 56) rr -= 56;
          int cc = wx * 7 + ix + 3; if (cc >= 56) cc -= 56;
          out[xbase + (size_t)(rr * 56 + cc) * 384 + c0 + l15] = acc[m][r] + bo;
        }
      }
  }
}

extern "C" void kernel_launch(void* const* d_in, const int* in_sizes, int n_in,
                              void* d_out, int out_size, void* d_ws, size_t ws_size,
                              hipStream_t stream) {
  const float* x    = (const float*)d_in[0];
  const float* wqkv = (const float*)d_in[1];
  const float* pos  = (const float*)d_in[2];
  const float* wout = (const float*)d_in[3];
  const float* bo   = (const float*)d_in[4];

  char* ws = (char*)d_ws;
  short* wqkvT = (short*)ws;                         ws += 1152 * 384 * 2;
  short* woutT = (short*)ws;                         ws += 384 * 384 * 2;
  float* btabT = (float*)ws;                         ws += 4 * 64 * 16 * 4 * 4;
  short* aoutg = (short*)ws;                         // [2048][49][384] bf16 (~77 MB)

  prep_all<<<1728, 256, 0, stream>>>(wqkv, wout, pos, wqkvT, woutT, btabT);
  swin_qkv_attn<<<6144, 512, 0, stream>>>(x, wqkvT, btabT, aoutg);
  swin_outproj<<<2048, 512, 0, stream>>>(aoutg, woutT, bo, (float*)d_out);
}

// Round 15
// 359.048 us; speedup vs baseline: 2.4151x; 2.4151x over previous
//
#include <hip/hip_runtime.h>

typedef __attribute__((ext_vector_type(8))) short short8;
typedef __attribute__((ext_vector_type(4))) int int4v;
typedef __attribute__((ext_vector_type(4))) float f32x4;

#define MFMA(a, b, c) __builtin_amdgcn_mfma_f32_16x16x32_bf16(a, b, c, 0, 0, 0)
#define SCALE 0.17677669529663687f

__device__ __forceinline__ short f2bf(float f) {
  union { float f; unsigned u; } v;
  v.f = f;
  unsigned r = v.u + 0x7fffu + ((v.u >> 16) & 1u);
  return (short)(r >> 16);
}

__device__ __forceinline__ unsigned cvt_pk(float lo, float hi) {
  unsigned r;
  asm("v_cvt_pk_bf16_f32 %0, %1, %2" : "=v"(r) : "v"(lo), "v"(hi));
  return r;
}

// K1 LDS map (81,456 B -> 2 blocks/CU exactly):
//   [0,16384)      vT[128][64] bf16, swizzle byte^=(d&7)<<4
//   [16384,28928)  Q[49][128] bf16, 256B/row, swizzle byte^=(row&7)<<4
//   [28928,41472)  K[49][128] bf16, same layout
//   [41472,81456)  x panel [49][XS_STR] bf16 (dead after P2; P scratch aliases it)
#define VT_OFF 0
#define Q_OFF  16384
#define K_OFF  28928
#define XP_OFF 41472
#define XS_STR 408    // 816B/row: %16==0; 2-way bank alias only (free)
#define AO_STR 392

// merged prep: weight transpose/cast + bias table in one launch
__global__ void prep_all(const float* __restrict__ wqkv,
                         const float* __restrict__ wout,
                         const float* __restrict__ pe,
                         short* __restrict__ wqkvT,
                         short* __restrict__ woutT,
                         float* __restrict__ btabT) {
  int i = blockIdx.x * 256 + threadIdx.x;
  if (i < 1152 * 384) {                  // wqkvT[n][k] = wqkv[k][n]; Q rows pre-scaled
    int n = i / 384, k = i - (i / 384) * 384;
    float w = wqkv[k * 1152 + n];
    if (n < 384) w *= SCALE;
    wqkvT[i] = f2bf(w);
  }
  if (i < 384 * 384) {                   // woutT[n][k] = wout[k][n]
    int n = i / 384, k = i - (i / 384) * 384;
    woutT[i] = f2bf(wout[k * 384 + n]);
  }
  if (i < 16384) {                       // btabT[t][i][c][nt] = bias(i, j=nt*16+c)
    int t = i >> 12;
    int ii = (i >> 6) & 63;
    int j = i & 63;
    float v;
    if (ii < 49 && j < 49) {
      int ai = ii / 7, bi = ii - ai * 7, aj = j / 7, bj = j - aj * 7;
      v = pe[(aj - ai + 6) * 13 + (bj - bi + 6)];
      if ((t & 1) && ((ii >= 28) != (j >= 28))) v = -1e30f;
      if ((t & 2) && ((bi >= 4) != (bj >= 4))) v = -1e30f;
    } else if (j < 49) {
      v = 0.f;
    } else {
      v = -1e30f;
    }
    btabT[((t * 64 + ii) * 16 + (j & 15)) * 4 + (j >> 4)] = v;
  }
}

// GEMM helpers (proven R6 form, acc[4][3]) — used by K2
#define GEMM_STEP(BUF)                                                        \
  {                                                                           \
    short8 a0 = *(const short8*)(pA[0] + k * 32);                             \
    short8 a1 = *(const short8*)(pA[1] + k * 32);                             \
    short8 a2 = *(const short8*)(pA[2] + k * 32);                             \
    short8 a3 = *(const short8*)(pA[3] + k * 32);                             \
    acc[0][0] = MFMA(a0, BUF[0], acc[0][0]);                                  \
    acc[1][0] = MFMA(a1, BUF[0], acc[1][0]);                                  \
    acc[2][0] = MFMA(a2, BUF[0], acc[2][0]);                                  \
    acc[3][0] = MFMA(a3, BUF[0], acc[3][0]);                                  \
    acc[0][1] = MFMA(a0, BUF[1], acc[0][1]);                                  \
    acc[1][1] = MFMA(a1, BUF[1], acc[1][1]);                                  \
    acc[2][1] = MFMA(a2, BUF[1], acc[2][1]);                                  \
    acc[3][1] = MFMA(a3, BUF[1], acc[3][1]);                                  \
    acc[0][2] = MFMA(a0, BUF[2], acc[0][2]);                                  \
    acc[1][2] = MFMA(a1, BUF[2], acc[1][2]);                                  \
    acc[2][2] = MFMA(a2, BUF[2], acc[2][2]);                                  \
    acc[3][2] = MFMA(a3, BUF[2], acc[3][2]);                                  \
  }

#define GEMM_PIPELINE()                                                       \
  _Pragma("unroll")                                                           \
  for (int n = 0; n < 3; ++n) bA[n] = *(const short8*)(pB[n]);                \
  _Pragma("unroll")                                                           \
  for (int n = 0; n < 3; ++n) bB[n] = *(const short8*)(pB[n] + 32);           \
  _Pragma("unroll")                                                           \
  for (int k = 0; k < 12; ++k) {                                              \
    if (k + 2 < 12) {                                                         \
      const int off = (k + 2) * 32;                                           \
      if (k % 3 == 0) {                                                       \
        _Pragma("unroll")                                                     \
        for (int n = 0; n < 3; ++n) bC[n] = *(const short8*)(pB[n] + off);    \
      } else if (k % 3 == 1) {                                                \
        _Pragma("unroll")                                                     \
        for (int n = 0; n < 3; ++n) bA[n] = *(const short8*)(pB[n] + off);    \
      } else {                                                                \
        _Pragma("unroll")                                                     \
        for (int n = 0; n < 3; ++n) bB[n] = *(const short8*)(pB[n] + off);    \
      }                                                                       \
    }                                                                         \
    if (k % 3 == 0) GEMM_STEP(bA)                                             \
    else if (k % 3 == 1) GEMM_STEP(bB)                                        \
    else GEMM_STEP(bC)                                                        \
  }

// ---------------- K1: QKV GEMM (4-head slice) + windowed attention ----------------
// (R13-proven: 289 us, 2 blocks/CU, no spill)
__global__ __launch_bounds__(512, 4) void swin_qkv_attn(
    const float* __restrict__ x, const short* __restrict__ wqkvT,
    const float* __restrict__ btabT, short* __restrict__ aout) {

  __shared__ short8 smem[5091];   // 81,456 B, see map above
  char* smc = (char*)smem;
  short* xpan = (short*)(smc + XP_OFF);

  const int tid = threadIdx.x;
  const int lane = tid & 63;
  const int wv = tid >> 6;
  const int l15 = lane & 15;
  const int lhi = lane >> 4;

  // XCD-chunked bijective swizzle (6144 % 8 == 0)
  const int bid = blockIdx.x;
  const int sw = (bid & 7) * 768 + (bid >> 3);
  const int g = sw - (sw / 3) * 3;
  const int bw = sw / 3;
  const int batch = bw >> 6;
  const int win = bw & 63;
  const int wy = win >> 3, wx = win & 7;

  const size_t xbase = (size_t)batch * (56 * 56 * 384);
  const f32x4 zf = {0.f, 0.f, 0.f, 0.f};

  // ---- Phase 1: x window -> x panel (one token per thread-octet) ----
  {
    const int tok = tid >> 3;          // 0..63
    const int sub = tid & 7;
    if (tok < 49) {
      int iy = (tok * 37) >> 8;
      int ix = tok - iy * 7;
      int rr = wy * 7 + iy + 3; if (rr >= 56) rr -= 56;
      int cc = wx * 7 + ix + 3; if (cc >= 56) cc -= 56;
      const float* xp = x + xbase + (size_t)(rr * 56 + cc) * 384;
#pragma unroll
      for (int j = 0; j < 6; ++j) {
        const int c8 = (sub + 8 * j) * 8;   // 8-float chunk
        const float4 fa = *(const float4*)(xp + c8);
        const float4 fb = *(const float4*)(xp + c8 + 4);
        int4v p;
        p.x = (int)cvt_pk(fa.x, fa.y);
        p.y = (int)cvt_pk(fa.z, fa.w);
        p.z = (int)cvt_pk(fb.x, fb.y);
        p.w = (int)cvt_pk(fb.z, fb.w);
        *(int4v*)(&xpan[tok * XS_STR + c8]) = p;
      }
    }
  }
  __syncthreads();   // barrier 1: x panel complete

  // ---- Phase 2: QKV GEMM for head group g ----
  f32x4 acc[4][3];
  const int n0 = wv * 48;
  {
    const short* pB[3];
#pragma unroll
    for (int n = 0; n < 3; ++n) {
      const int c0 = n0 + n * 16;
      const int seg = c0 >> 7;             // 0=q 1=k 2=v
      const int hloc = (c0 >> 5) & 3;
      const int wrow = seg * 384 + (g * 4 + hloc) * 32 + (c0 & 31);
      pB[n] = wqkvT + (size_t)(wrow + l15) * 384 + lhi * 8;
    }
#pragma unroll
    for (int m = 0; m < 4; ++m)
#pragma unroll
      for (int n = 0; n < 3; ++n) acc[m][n] = zf;

    const short* pA[4];
#pragma unroll
    for (int m = 0; m < 4; ++m) {
      int row = m * 16 + l15;
      int rc = row < 49 ? row : 48;
      pA[m] = &xpan[rc * XS_STR + lhi * 8];
    }

#pragma unroll
    for (int k = 0; k < 12; ++k) {
      const short8 b0 = *(const short8*)(pB[0] + k * 32);
      const short8 b1 = *(const short8*)(pB[1] + k * 32);
      const short8 b2 = *(const short8*)(pB[2] + k * 32);
#pragma unroll
      for (int m = 0; m < 4; ++m) {
        const short8 a = *(const short8*)(pA[m] + k * 32);
        acc[m][0] = MFMA(a, b0, acc[m][0]);
        acc[m][1] = MFMA(a, b1, acc[m][1]);
        acc[m][2] = MFMA(a, b2, acc[m][2]);
      }
    }
  }

  // ---- Epilogue: acc -> vT | Q | K (disjoint from x panel -> no barrier before) ----
  {
#pragma unroll
    for (int n = 0; n < 3; ++n) {
      const int c0 = n0 + n * 16;
      if (c0 < 256) {
#pragma unroll
        for (int m = 0; m < 4; ++m)
#pragma unroll
          for (int r = 0; r < 4; ++r) {
            const int row = m * 16 + lhi * 4 + r;
            if (row < 49) {
              const int f = c0 + l15;                 // 0..255: Q then K
              const int base = (f < 128) ? Q_OFF : K_OFF;
              const int fo = (f & 127) * 2;
              *(short*)(smc + base + row * 256 + (fo ^ ((row & 7) << 4))) =
                  f2bf(acc[m][n][r]);
            }
          }
      } else {
        // V: pack row pairs with cvt_pk (no row guard; j>=49 garbage killed by P=0)
        const int d = c0 - 256 + l15;
        char* vrow = smc + VT_OFF + d * 128;
        const int dx = (d & 7) << 4;
#pragma unroll
        for (int m = 0; m < 4; ++m)
#pragma unroll
          for (int r = 0; r < 4; r += 2) {
            const int row = m * 16 + lhi * 4 + r;
            const unsigned pk = cvt_pk(acc[m][n][r], acc[m][n][r + 1]);
            *(unsigned*)(vrow + ((2 * row) ^ dx)) = pk;
          }
      }
    }
  }
  __syncthreads();   // barrier 2: Q/K/vT complete — phase 3 barrier-free

  // ---- Phase 3: attention — one task per wave, fully desynced ----
  {
    const int hl = wv >> 1;
    const int mh = wv & 1;
    const int tt = (wy == 7 ? 1 : 0) | (wx == 7 ? 2 : 0);

    f32x4 bb[2][4];
#pragma unroll
    for (int mi = 0; mi < 2; ++mi)
#pragma unroll
      for (int r = 0; r < 4; ++r) {
        const int i = mh * 32 + mi * 16 + lhi * 4 + r;
        bb[mi][r] = *(const f32x4*)(&btabT[((tt * 64 + i) * 16 + l15) * 4]);
      }

    short8 qa[2];
#pragma unroll
    for (int mi = 0; mi < 2; ++mi) {
      int row = mh * 32 + mi * 16 + l15;
      int rc = row < 49 ? row : 48;
      qa[mi] = *(const short8*)(smc + Q_OFF + rc * 256 +
                                ((hl * 64 + lhi * 16) ^ ((rc & 7) << 4)));
    }
    f32x4 s[2][4];
#pragma unroll
    for (int nt = 0; nt < 4; ++nt) {
      int jr = nt * 16 + l15;
      int jc = jr < 49 ? jr : 48;          // garbage cols killed by bias -1e30
      short8 kb = *(const short8*)(smc + K_OFF + jc * 256 +
                                   ((hl * 64 + lhi * 16) ^ ((jc & 7) << 4)));
#pragma unroll
      for (int mi = 0; mi < 2; ++mi) s[mi][nt] = MFMA(qa[mi], kb, zf);
    }

#pragma unroll
    for (int mi = 0; mi < 2; ++mi)
#pragma unroll
      for (int r = 0; r < 4; ++r)
#pragma unroll
        for (int nt = 0; nt < 4; ++nt)
          s[mi][nt][r] += bb[mi][r][nt];

#pragma unroll
    for (int mi = 0; mi < 2; ++mi)
#pragma unroll
      for (int r = 0; r < 4; ++r) {
        float mx = fmaxf(fmaxf(s[mi][0][r], s[mi][1][r]),
                         fmaxf(s[mi][2][r], s[mi][3][r]));
        mx = fmaxf(mx, __shfl_xor(mx, 1));
        mx = fmaxf(mx, __shfl_xor(mx, 2));
        mx = fmaxf(mx, __shfl_xor(mx, 4));
        mx = fmaxf(mx, __shfl_xor(mx, 8));
        float p0 = __expf(s[mi][0][r] - mx);
        float p1 = __expf(s[mi][1][r] - mx);
        float p2 = __expf(s[mi][2][r] - mx);
        float p3 = __expf(s[mi][3][r] - mx);
        float sum = p0 + p1 + p2 + p3;
        sum += __shfl_xor(sum, 1);
        sum += __shfl_xor(sum, 2);
        sum += __shfl_xor(sum, 4);
        sum += __shfl_xor(sum, 8);
        const float inv = __builtin_amdgcn_rcpf(sum);
        s[mi][0][r] = p0 * inv;
        s[mi][1][r] = p1 * inv;
        s[mi][2][r] = p2 * inv;
        s[mi][3][r] = p3 * inv;
      }

    // P scratch aliases the dead x panel — wave-private, no barrier needed
    char* Pb = smc + XP_OFF + wv * 2304;   // 16 rows x 144B
    f32x4 O[2][2];
#pragma unroll
    for (int mi = 0; mi < 2; ++mi) {
#pragma unroll
      for (int r = 0; r < 4; ++r) {
        const int rowl = lhi * 4 + r;
        short* pr = (short*)(Pb + rowl * 144);
        pr[ 0 + l15] = f2bf(s[mi][0][r]);
        pr[16 + l15] = f2bf(s[mi][1][r]);
        pr[32 + l15] = f2bf(s[mi][2][r]);
        pr[48 + l15] = f2bf(s[mi][3][r]);
      }
      const short8 pa0 = *(const short8*)(Pb + l15 * 144 +  0 + lhi * 16);
      const short8 pa1 = *(const short8*)(Pb + l15 * 144 + 64 + lhi * 16);
#pragma unroll
      for (int n2 = 0; n2 < 2; ++n2) {
        const int dg = hl * 32 + n2 * 16 + l15;
        const short8 v0 = *(const short8*)(smc + VT_OFF + dg * 128 +
                              ((lhi * 16) ^ ((dg & 7) << 4)));
        const short8 v1 = *(const short8*)(smc + VT_OFF + dg * 128 +
                              ((64 + lhi * 16) ^ ((dg & 7) << 4)));
        O[mi][n2] = MFMA(pa0, v0, zf);
        O[mi][n2] = MFMA(pa1, v1, O[mi][n2]);
      }
    }

    short* ab = aout + (size_t)bw * (49 * 384) + (g * 4 + hl) * 32;
#pragma unroll
    for (int mi = 0; mi < 2; ++mi)
#pragma unroll
      for (int n2 = 0; n2 < 2; ++n2)
#pragma unroll
        for (int r = 0; r < 4; ++r) {
          int row = mh * 32 + mi * 16 + lhi * 4 + r;
          if (row < 49) ab[row * 384 + n2 * 16 + l15] = f2bf(O[mi][n2][r]);
        }
  }
}

// ---------------- K2: out-proj (R13-proven form) ----------------
__global__ __launch_bounds__(512, 4) void swin_outproj(
    const short* __restrict__ aout, const short* __restrict__ woutT,
    const float* __restrict__ bout, float* __restrict__ out) {

  __shared__ short ao[49 * AO_STR];   // 38,416 B

  const int tid = threadIdx.x;
  const int lane = tid & 63;
  const int wv = tid >> 6;
  const int l15 = lane & 15;
  const int lhi = lane >> 4;

  const int bw = blockIdx.x;
  const int batch = bw >> 6;
  const int win = bw & 63;
  const int wy = win >> 3, wx = win & 7;

  const size_t xbase = (size_t)batch * (56 * 56 * 384);
  const f32x4 zf = {0.f, 0.f, 0.f, 0.f};

  const short* abg = aout + (size_t)bw * (49 * 384);
  for (int t = tid; t < 49 * 48; t += 512) {
    int row = t / 48;
    int seg = t - row * 48;
    *(short8*)(&ao[row * AO_STR + seg * 8]) = *(const short8*)(&abg[row * 384 + seg * 8]);
  }
  __syncthreads();

  {
    const int n0 = wv * 48;
    f32x4 acc[4][3];
#pragma unroll
    for (int m = 0; m < 4; ++m)
#pragma unroll
      for (int n = 0; n < 3; ++n) acc[m][n] = zf;

    const short* pB[3];
#pragma unroll
    for (int n = 0; n < 3; ++n)
      pB[n] = woutT + (size_t)(n0 + n * 16 + l15) * 384 + lhi * 8;

    const short* pA[4];
#pragma unroll
    for (int m = 0; m < 4; ++m) {
      int row = m * 16 + l15;
      int rc = row < 49 ? row : 48;
      pA[m] = &ao[rc * AO_STR + lhi * 8];
    }

    short8 bA[3], bB[3], bC[3];
    GEMM_PIPELINE()

    float bo[3];
#pragma unroll
    for (int n = 0; n < 3; ++n) bo[n] = bout[n0 + n * 16 + l15];

#pragma unroll
    for (int m = 0; m < 4; ++m)
#pragma unroll
      for (int r = 0; r < 4; ++r) {
        const int row = m * 16 + lhi * 4 + r;
        if (row < 49) {
          int iy = (row * 37) >> 8, ix = row - iy * 7;
          int rr = wy * 7 + iy + 3; if (rr >= 56) rr -= 56;
          int cc = wx * 7 + ix + 3; if (cc >= 56) cc -= 56;
          float* dst = out + xbase + (size_t)(rr * 56 + cc) * 384 + n0;
#pragma unroll
          for (int n = 0; n < 3; ++n) dst[n * 16 + l15] = acc[m][n][r] + bo[n];
        }
      }
  }
}

extern "C" void kernel_launch(void* const* d_in, const int* in_sizes, int n_in,
                              void* d_out, int out_size, void* d_ws, size_t ws_size,
                              hipStream_t stream) {
  const float* x    = (const float*)d_in[0];
  const float* wqkv = (const float*)d_in[1];
  const float* pos  = (const float*)d_in[2];
  const float* wout = (const float*)d_in[3];
  const float* bo   = (const float*)d_in[4];

  char* ws = (char*)d_ws;
  short* wqkvT = (short*)ws;                         ws += 1152 * 384 * 2;
  short* woutT = (short*)ws;                         ws += 384 * 384 * 2;
  float* btabT = (float*)ws;                         ws += 4 * 64 * 16 * 4 * 4;
  short* aoutg = (short*)ws;                         // [2048][49][384] bf16 (~77 MB)

  prep_all<<<1728, 256, 0, stream>>>(wqkv, wout, pos, wqkvT, woutT, btabT);
  swin_qkv_attn<<<6144, 512, 0, stream>>>(x, wqkvT, btabT, aoutg);
  swin_outproj<<<2048, 512, 0, stream>>>(aoutg, woutT, bo, (float*)d_out);
}